// Round 1
// baseline (305.509 us; speedup 1.0000x reference)
//
#include <hip/hip_runtime.h>
#include <hip/hip_bf16.h>

// Clifford Cl(3,0) geometric product, basis order:
//   0:1  1:e1  2:e2  3:e3  4:e12  5:e13  6:e23  7:e123
// Structure constants hardcoded (each a_i*b_j lands in exactly one c_k with sign +-1).
// Memory-bound: 384 MiB total traffic -> ~61 us floor at 6.3 TB/s.

__global__ __launch_bounds__(256) void CliffordProduct_85452669321821_kernel(
    const float4* __restrict__ a, const float4* __restrict__ b,
    float4* __restrict__ out, int n) {
    int t = blockIdx.x * blockDim.x + threadIdx.x;
    if (t >= n) return;

    float4 al = a[2 * t];
    float4 ah = a[2 * t + 1];
    float4 bl = b[2 * t];
    float4 bh = b[2 * t + 1];

    float A0 = al.x, A1 = al.y, A2 = al.z, A3 = al.w;
    float A4 = ah.x, A5 = ah.y, A6 = ah.z, A7 = ah.w;
    float B0 = bl.x, B1 = bl.y, B2 = bl.z, B3 = bl.w;
    float B4 = bh.x, B5 = bh.y, B6 = bh.z, B7 = bh.w;

    float c0 = A0*B0 + A1*B1 + A2*B2 + A3*B3 - A4*B4 - A5*B5 - A6*B6 - A7*B7;
    float c1 = A0*B1 + A1*B0 - A2*B4 + A4*B2 - A3*B5 + A5*B3 - A6*B7 - A7*B6;
    float c2 = A0*B2 + A2*B0 + A1*B4 - A4*B1 - A3*B6 + A6*B3 + A5*B7 + A7*B5;
    float c3 = A0*B3 + A3*B0 + A1*B5 - A5*B1 + A2*B6 - A6*B2 - A4*B7 - A7*B4;
    float c4 = A0*B4 + A4*B0 + A1*B2 - A2*B1 - A5*B6 + A6*B5 + A3*B7 + A7*B3;
    float c5 = A0*B5 + A5*B0 + A1*B3 - A3*B1 + A4*B6 - A6*B4 - A2*B7 - A7*B2;
    float c6 = A0*B6 + A6*B0 + A2*B3 - A3*B2 - A4*B5 + A5*B4 + A1*B7 + A7*B1;
    float c7 = A0*B7 + A7*B0 + A1*B6 + A6*B1 - A2*B5 - A5*B2 + A3*B4 + A4*B3;

    out[2 * t]     = make_float4(c0, c1, c2, c3);
    out[2 * t + 1] = make_float4(c4, c5, c6, c7);
}

extern "C" void kernel_launch(void* const* d_in, const int* in_sizes, int n_in,
                              void* d_out, int out_size, void* d_ws, size_t ws_size,
                              hipStream_t stream) {
    const float4* a = (const float4*)d_in[0];
    const float4* b = (const float4*)d_in[1];
    float4* out = (float4*)d_out;
    int n = in_sizes[0] / 8;  // number of multivectors
    int threads = 256;
    int blocks = (n + threads - 1) / threads;
    CliffordProduct_85452669321821_kernel<<<blocks, threads, 0, stream>>>(a, b, out, n);
}

// Round 2
// 305.390 us; speedup vs baseline: 1.0004x; 1.0004x over previous
//
#include <hip/hip_runtime.h>
#include <hip/hip_bf16.h>

// Clifford Cl(3,0) geometric product. Memory-bound: ~402 MB logical traffic.
// R1 lesson: per-thread {2t, 2t+1} float4 accesses give 50% line utilization
// per VMEM instruction -> 2.5 TB/s. Fix: LDS-staged, so every global load/store
// instruction is lane-dense (lane i at byte 16*i, 1 KiB per wave instruction).

__global__ __launch_bounds__(256) void CliffordProduct_85452669321821_kernel(
    const float4* __restrict__ a, const float4* __restrict__ b,
    float4* __restrict__ out, int n4) {
    // n4 = number of float4 elements (= 2 * n_multivectors)
    __shared__ float4 la[512];
    __shared__ float4 lb[512];

    const int tid = threadIdx.x;
    const int g0 = blockIdx.x * 512;

    // Stage in: dense per-instruction addresses (lane i -> byte 16i).
    if (g0 + tid < n4)       la[tid]       = a[g0 + tid];
    if (g0 + 256 + tid < n4) la[tid + 256] = a[g0 + 256 + tid];
    if (g0 + tid < n4)       lb[tid]       = b[g0 + tid];
    if (g0 + 256 + tid < n4) lb[tid + 256] = b[g0 + 256 + tid];
    __syncthreads();

    // Each thread computes multivector (g0/2 + tid): LDS reads at byte 32i
    // -> 2-way bank aliasing, free on gfx950 (m136).
    float4 al = la[2 * tid];
    float4 ah = la[2 * tid + 1];
    float4 bl = lb[2 * tid];
    float4 bh = lb[2 * tid + 1];

    float A0 = al.x, A1 = al.y, A2 = al.z, A3 = al.w;
    float A4 = ah.x, A5 = ah.y, A6 = ah.z, A7 = ah.w;
    float B0 = bl.x, B1 = bl.y, B2 = bl.z, B3 = bl.w;
    float B4 = bh.x, B5 = bh.y, B6 = bh.z, B7 = bh.w;

    float c0 = A0*B0 + A1*B1 + A2*B2 + A3*B3 - A4*B4 - A5*B5 - A6*B6 - A7*B7;
    float c1 = A0*B1 + A1*B0 - A2*B4 + A4*B2 - A3*B5 + A5*B3 - A6*B7 - A7*B6;
    float c2 = A0*B2 + A2*B0 + A1*B4 - A4*B1 - A3*B6 + A6*B3 + A5*B7 + A7*B5;
    float c3 = A0*B3 + A3*B0 + A1*B5 - A5*B1 + A2*B6 - A6*B2 - A4*B7 - A7*B4;
    float c4 = A0*B4 + A4*B0 + A1*B2 - A2*B1 - A5*B6 + A6*B5 + A3*B7 + A7*B3;
    float c5 = A0*B5 + A5*B0 + A1*B3 - A3*B1 + A4*B6 - A6*B4 - A2*B7 - A7*B2;
    float c6 = A0*B6 + A6*B0 + A2*B3 - A3*B2 - A4*B5 + A5*B4 + A1*B7 + A7*B1;
    float c7 = A0*B7 + A7*B0 + A1*B6 + A6*B1 - A2*B5 - A5*B2 + A3*B4 + A4*B3;

    // Stage out through LDS (reuse la): write at byte 32i (2-way, free),
    // then dense global stores.
    __syncthreads();
    la[2 * tid]     = make_float4(c0, c1, c2, c3);
    la[2 * tid + 1] = make_float4(c4, c5, c6, c7);
    __syncthreads();

    if (g0 + tid < n4)       out[g0 + tid]       = la[tid];
    if (g0 + 256 + tid < n4) out[g0 + 256 + tid] = la[tid + 256];
}

extern "C" void kernel_launch(void* const* d_in, const int* in_sizes, int n_in,
                              void* d_out, int out_size, void* d_ws, size_t ws_size,
                              hipStream_t stream) {
    const float4* a = (const float4*)d_in[0];
    const float4* b = (const float4*)d_in[1];
    float4* out = (float4*)d_out;
    int n4 = in_sizes[0] / 4;           // total float4 elements
    int blocks = (n4 + 511) / 512;      // 512 float4 per block (256 multivectors)
    CliffordProduct_85452669321821_kernel<<<blocks, 256, 0, stream>>>(a, b, out, n4);
}